// Round 1
// baseline (436.074 us; speedup 1.0000x reference)
//
#include <hip/hip_runtime.h>
#include <hip/hip_bf16.h>

typedef __hip_bfloat16 bf16;
typedef __attribute__((ext_vector_type(8))) short short8;
typedef __attribute__((ext_vector_type(4))) float floatx4;

struct __align__(8) bf16x4 { bf16 v[4]; };

#define LOG2E 1.4426950408889634f

__device__ __forceinline__ void gload_lds16(const void* g, void* l) {
  __builtin_amdgcn_global_load_lds(
      (const __attribute__((address_space(1))) void*)g,
      (__attribute__((address_space(3))) void*)l, 16, 0, 0);
}

__device__ __forceinline__ floatx4 mfma16(short8 a, short8 b, floatx4 c) {
  return __builtin_amdgcn_mfma_f32_16x16x32_bf16(a, b, c, 0, 0, 0);
}

// ---------------------------------------------------------------- convert x
__global__ __launch_bounds__(256) void convert_x(const float* __restrict__ x,
                                                 bf16* __restrict__ xb) {
  int i = blockIdx.x * 256 + threadIdx.x;          // group of 4 elems
  float4 v = ((const float4*)x)[i];
  bf16x4 o;
  o.v[0] = __float2bfloat16(v.x);
  o.v[1] = __float2bfloat16(v.y);
  o.v[2] = __float2bfloat16(v.z);
  o.v[3] = __float2bfloat16(v.w);
  ((bf16x4*)xb)[i] = o;
}

// ------------------------------------------- transpose+convert weight (f32->bf16)
// W: [K][N] f32 row-major.  WT: [N][K] bf16 row-major.  grid (N/64, K/64)
__global__ __launch_bounds__(256) void transpose_w(const float* __restrict__ W,
                                                   bf16* __restrict__ WT,
                                                   int K, int N) {
  __shared__ float t[64][65];
  const int n0 = blockIdx.x * 64, k0 = blockIdx.y * 64;
  const int tid = threadIdx.x;
#pragma unroll
  for (int i = 0; i < 16; ++i) {
    int idx = i * 256 + tid;
    int r = idx >> 6, c = idx & 63;
    t[r][c] = W[(size_t)(k0 + r) * N + n0 + c];
  }
  __syncthreads();
#pragma unroll
  for (int i = 0; i < 16; ++i) {
    int idx = i * 256 + tid;
    int r = idx >> 6, c = idx & 63;
    WT[(size_t)(n0 + r) * K + k0 + c] = __float2bfloat16(t[c][r]);
  }
}

// ------------------------------------------------ V [bh][S][64] -> Vt [bh][64][S]
__global__ __launch_bounds__(256) void transpose_v(const bf16* __restrict__ V,
                                                   bf16* __restrict__ Vt) {
  __shared__ bf16 t[64][72];
  const int bh = blockIdx.y;
  const int s0 = blockIdx.x * 64;
  const bf16* src = V + (size_t)bh * 2048 * 64;
  bf16* dst = Vt + (size_t)bh * 64 * 2048;
  const int tid = threadIdx.x;
#pragma unroll
  for (int i = 0; i < 16; ++i) {
    int idx = i * 256 + tid;
    int r = idx >> 6, c = idx & 63;
    t[r][c] = src[(size_t)(s0 + r) * 64 + c];
  }
  __syncthreads();
#pragma unroll
  for (int i = 0; i < 16; ++i) {
    int idx = i * 256 + tid;
    int r = idx >> 6, c = idx & 63;
    dst[(size_t)r * 2048 + s0 + c] = t[c][r];
  }
}

// ---------------------------------------------------------------- GEMM (BT form)
// C[m][n] = sum_k A[m][k] * BT[n][k]   A:[M][K] bf16, BT:[N][K] bf16
// MODE 0: QKV epilogue (bias q/k/v, scatter to [B][H][S][HD] bf16, V->C2)
// MODE 1: gelu(acc + bias0) -> bf16 C0 [M][N]
// MODE 2: acc + bias0 -> f32 C0 [M][N]
template <int MODE>
__global__ __launch_bounds__(256) void gemm_bt(
    const bf16* __restrict__ A, const bf16* __restrict__ BT,
    const float* __restrict__ bias0, const float* __restrict__ bias1,
    const float* __restrict__ bias2, void* __restrict__ C0,
    void* __restrict__ C1, void* __restrict__ C2, int M, int N, int K) {
  __shared__ bf16 As[128][64];
  __shared__ bf16 Bs[128][64];
  const int tid = threadIdx.x;
  const int wid = tid >> 6, lane = tid & 63;
  const int l16 = lane & 15, lhi = lane >> 4;
  const int brow = blockIdx.y * 128, bcol = blockIdx.x * 128;
  const int wr = (wid >> 1) * 64, wc = (wid & 1) * 64;
  floatx4 acc[4][4] = {};

  for (int kt = 0; kt < K; kt += 64) {
    __syncthreads();
#pragma unroll
    for (int i = 0; i < 4; ++i) {
      int f = i * 256 + tid;
      int r = f >> 3, c = (f & 7) * 8;
      gload_lds16(A + (size_t)(brow + r) * K + kt + c, (char*)&As[0][0] + (size_t)f * 16);
      gload_lds16(BT + (size_t)(bcol + r) * K + kt + c, (char*)&Bs[0][0] + (size_t)f * 16);
    }
    __syncthreads();
#pragma unroll
    for (int kk = 0; kk < 2; ++kk) {
      const int kc = kk * 32 + lhi * 8;
      short8 af[4], bfr[4];
#pragma unroll
      for (int m = 0; m < 4; ++m) af[m] = *(const short8*)&As[wr + m * 16 + l16][kc];
#pragma unroll
      for (int n = 0; n < 4; ++n) bfr[n] = *(const short8*)&Bs[wc + n * 16 + l16][kc];
#pragma unroll
      for (int m = 0; m < 4; ++m)
#pragma unroll
        for (int n = 0; n < 4; ++n) acc[m][n] = mfma16(af[m], bfr[n], acc[m][n]);
    }
  }

  // epilogue: C/D layout col = lane&15, row = (lane>>4)*4 + r
#pragma unroll
  for (int m = 0; m < 4; ++m) {
    const int rowb = brow + wr + m * 16 + lhi * 4;
#pragma unroll
    for (int n = 0; n < 4; ++n) {
      const int col = bcol + wc + n * 16 + l16;
#pragma unroll
      for (int r = 0; r < 4; ++r) {
        float v = acc[m][n][r];
        const int gr = rowb + r;
        if constexpr (MODE == 0) {
          const int which = col >> 10;        // 0:Q 1:K 2:V
          const int nl = col & 1023;
          const float* bp = (which == 0) ? bias0 : (which == 1) ? bias1 : bias2;
          v += bp[nl];
          const int b = gr >> 11, s = gr & 2047;
          const int h = nl >> 6, hd = nl & 63;
          const size_t dst = ((size_t)(b * 16 + h) * 2048 + s) * 64 + hd;
          bf16* out = (which == 0) ? (bf16*)C0 : (which == 1) ? (bf16*)C1 : (bf16*)C2;
          out[dst] = __float2bfloat16(v);
        } else if constexpr (MODE == 1) {
          v += bias0[col];
          float gchar = 0.5f * v * (1.0f + erff(v * 0.70710678118654752f));
          ((bf16*)C0)[(size_t)gr * N + col] = __float2bfloat16(gchar);
        } else {
          v += bias0[col];
          ((float*)C0)[(size_t)gr * N + col] = v;
        }
      }
    }
  }
}

// ---------------------------------------------------------------- flash attention
// Q,K: [bh][S][64] bf16 ; Vt: [bh][64][S] bf16 ; attn out: [B*S][1024] bf16
// grid: (S/128, 32) block 256
__global__ __launch_bounds__(256) void flash_attn(const bf16* __restrict__ Q,
                                                  const bf16* __restrict__ Kb,
                                                  const bf16* __restrict__ Vt,
                                                  bf16* __restrict__ attn) {
  __shared__ bf16 Qs[128][64];
  __shared__ bf16 Ks[64][64];
  __shared__ bf16 Vs[64][64];
  __shared__ bf16 Ps[4][32][64];
  const int tid = threadIdx.x, wid = tid >> 6, lane = tid & 63;
  const int l16 = lane & 15, lhi = lane >> 4;
  const int qt = blockIdx.x, bh = blockIdx.y;
  const bf16* Qbh = Q + (size_t)bh * 2048 * 64;
  const bf16* Kbh = Kb + (size_t)bh * 2048 * 64;
  const bf16* Vbh = Vt + (size_t)bh * 64 * 2048;

  // stage Q tile once
#pragma unroll
  for (int i = 0; i < 4; ++i) {
    int f = i * 256 + tid;
    int r = f >> 3, c = (f & 7) * 8;
    gload_lds16(Qbh + (size_t)(qt * 128 + r) * 64 + c, (char*)&Qs[0][0] + (size_t)f * 16);
  }
  __syncthreads();
  short8 qf[2][2];
#pragma unroll
  for (int fr = 0; fr < 2; ++fr)
#pragma unroll
    for (int kk = 0; kk < 2; ++kk)
      qf[fr][kk] = *(const short8*)&Qs[wid * 32 + fr * 16 + l16][kk * 32 + lhi * 8];

  floatx4 o[2][4] = {};
  float mrow[2][4], lrow[2][4];
#pragma unroll
  for (int fr = 0; fr < 2; ++fr)
#pragma unroll
    for (int r = 0; r < 4; ++r) { mrow[fr][r] = -1e30f; lrow[fr][r] = 0.0f; }

  for (int kv = 0; kv < 32; ++kv) {
    __syncthreads();   // prev PV reads done before K/V overwrite
#pragma unroll
    for (int i = 0; i < 2; ++i) {
      int f = i * 256 + tid;
      int r = f >> 3, c = (f & 7) * 8;
      gload_lds16(Kbh + (size_t)(kv * 64 + r) * 64 + c, (char*)&Ks[0][0] + (size_t)f * 16);
      gload_lds16(Vbh + (size_t)r * 2048 + kv * 64 + c, (char*)&Vs[0][0] + (size_t)f * 16);
    }
    __syncthreads();

    // scores: wave owns 32 q rows x 64 k cols
    floatx4 sf[2][4] = {};
#pragma unroll
    for (int kk = 0; kk < 2; ++kk) {
      const int kc = kk * 32 + lhi * 8;
      short8 kf[4];
#pragma unroll
      for (int fc = 0; fc < 4; ++fc) kf[fc] = *(const short8*)&Ks[fc * 16 + l16][kc];
#pragma unroll
      for (int fr = 0; fr < 2; ++fr)
#pragma unroll
        for (int fc = 0; fc < 4; ++fc) sf[fr][fc] = mfma16(qf[fr][kk], kf[fc], sf[fr][fc]);
    }

    // online softmax (rows spread over 16-lane col groups)
#pragma unroll
    for (int fr = 0; fr < 2; ++fr) {
#pragma unroll
      for (int r = 0; r < 4; ++r) {
        float mx = -1e30f;
#pragma unroll
        for (int fc = 0; fc < 4; ++fc) mx = fmaxf(mx, sf[fr][fc][r]);
#pragma unroll
        for (int d = 1; d < 16; d <<= 1) mx = fmaxf(mx, __shfl_xor(mx, d));
        mx *= 0.125f;
        const float mold = mrow[fr][r];
        const float mnew = fmaxf(mold, mx);
        const float corr = exp2f((mold - mnew) * LOG2E);
        float rsum = 0.0f;
#pragma unroll
        for (int fc = 0; fc < 4; ++fc) {
          float p = exp2f((sf[fr][fc][r] * 0.125f - mnew) * LOG2E);
          sf[fr][fc][r] = p;
          rsum += p;
        }
#pragma unroll
        for (int d = 1; d < 16; d <<= 1) rsum += __shfl_xor(rsum, d);
        lrow[fr][r] = lrow[fr][r] * corr + rsum;
        mrow[fr][r] = mnew;
#pragma unroll
        for (int fc = 0; fc < 4; ++fc) o[fr][fc][r] *= corr;
      }
    }

    // P -> per-wave LDS (C-layout positions)
#pragma unroll
    for (int fr = 0; fr < 2; ++fr)
#pragma unroll
      for (int fc = 0; fc < 4; ++fc)
#pragma unroll
        for (int r = 0; r < 4; ++r)
          Ps[wid][fr * 16 + lhi * 4 + r][fc * 16 + l16] = __float2bfloat16(sf[fr][fc][r]);

    // PV
#pragma unroll
    for (int kk = 0; kk < 2; ++kk) {
      const int kc = kk * 32 + lhi * 8;
      short8 pf[2], vf[4];
#pragma unroll
      for (int fr = 0; fr < 2; ++fr) pf[fr] = *(const short8*)&Ps[wid][fr * 16 + l16][kc];
#pragma unroll
      for (int fc = 0; fc < 4; ++fc) vf[fc] = *(const short8*)&Vs[fc * 16 + l16][kc];
#pragma unroll
      for (int fr = 0; fr < 2; ++fr)
#pragma unroll
        for (int fc = 0; fc < 4; ++fc) o[fr][fc] = mfma16(pf[fr], vf[fc], o[fr][fc]);
    }
  }

  // write out: attn token-major [b*2048+s][h*64+hd]
  const int b = bh >> 4, h = bh & 15;
#pragma unroll
  for (int fr = 0; fr < 2; ++fr)
#pragma unroll
    for (int r = 0; r < 4; ++r) {
      const float inv = 1.0f / lrow[fr][r];
      const int s = qt * 128 + wid * 32 + fr * 16 + lhi * 4 + r;
      const size_t rowbase = (size_t)(b * 2048 + s) * 1024 + h * 64;
#pragma unroll
      for (int fc = 0; fc < 4; ++fc)
        attn[rowbase + fc * 16 + l16] = __float2bfloat16(o[fr][fc][r] * inv);
    }
}

// ---------------------------------------------------------------- LN1 (attn + x)
__global__ __launch_bounds__(256) void ln_res(const bf16* __restrict__ attn,
                                              const float* __restrict__ x,
                                              const float* __restrict__ g,
                                              const float* __restrict__ be,
                                              bf16* __restrict__ out) {
  __shared__ float sa[4], sb[4];
  const int row = blockIdx.x;
  const size_t base = (size_t)row * 1024;
  const int tid = threadIdx.x;
  const int c0 = tid * 4;
  float4 xv = *(const float4*)(x + base + c0);
  bf16x4 av = *(const bf16x4*)(attn + base + c0);
  float v[4];
  v[0] = xv.x + __bfloat162float(av.v[0]);
  v[1] = xv.y + __bfloat162float(av.v[1]);
  v[2] = xv.z + __bfloat162float(av.v[2]);
  v[3] = xv.w + __bfloat162float(av.v[3]);
  float s = v[0] + v[1] + v[2] + v[3];
  float ss = v[0]*v[0] + v[1]*v[1] + v[2]*v[2] + v[3]*v[3];
#pragma unroll
  for (int d = 32; d > 0; d >>= 1) { s += __shfl_down(s, d); ss += __shfl_down(ss, d); }
  const int wid = tid >> 6, lane = tid & 63;
  if (lane == 0) { sa[wid] = s; sb[wid] = ss; }
  __syncthreads();
  if (tid == 0) { sa[0] = sa[0]+sa[1]+sa[2]+sa[3]; sb[0] = sb[0]+sb[1]+sb[2]+sb[3]; }
  __syncthreads();
  s = sa[0]; ss = sb[0];
  const float mu = s * (1.0f / 1024.0f);
  const float var = ss * (1.0f / 1024.0f) - mu * mu;
  const float rs = rsqrtf(var + 1e-5f);
  float4 gv = *(const float4*)(g + c0);
  float4 bv = *(const float4*)(be + c0);
  bf16x4 o;
  o.v[0] = __float2bfloat16((v[0]-mu)*rs*gv.x + bv.x);
  o.v[1] = __float2bfloat16((v[1]-mu)*rs*gv.y + bv.y);
  o.v[2] = __float2bfloat16((v[2]-mu)*rs*gv.z + bv.z);
  o.v[3] = __float2bfloat16((v[3]-mu)*rs*gv.w + bv.w);
  *(bf16x4*)(out + base + c0) = o;
}

// ---------------------------------------------------------------- LN2 (2*ffn)
__global__ __launch_bounds__(256) void ln2_kernel(const float* __restrict__ y,
                                                  const float* __restrict__ g,
                                                  const float* __restrict__ be,
                                                  float* __restrict__ out) {
  __shared__ float sa[4], sb[4];
  const int row = blockIdx.x;
  const size_t base = (size_t)row * 1024;
  const int tid = threadIdx.x;
  const int c0 = tid * 4;
  float4 yv = *(const float4*)(y + base + c0);
  float v[4] = {2.0f * yv.x, 2.0f * yv.y, 2.0f * yv.z, 2.0f * yv.w};
  float s = v[0] + v[1] + v[2] + v[3];
  float ss = v[0]*v[0] + v[1]*v[1] + v[2]*v[2] + v[3]*v[3];
#pragma unroll
  for (int d = 32; d > 0; d >>= 1) { s += __shfl_down(s, d); ss += __shfl_down(ss, d); }
  const int wid = tid >> 6, lane = tid & 63;
  if (lane == 0) { sa[wid] = s; sb[wid] = ss; }
  __syncthreads();
  if (tid == 0) { sa[0] = sa[0]+sa[1]+sa[2]+sa[3]; sb[0] = sb[0]+sb[1]+sb[2]+sb[3]; }
  __syncthreads();
  s = sa[0]; ss = sb[0];
  const float mu = s * (1.0f / 1024.0f);
  const float var = ss * (1.0f / 1024.0f) - mu * mu;
  const float rs = rsqrtf(var + 1e-5f);
  float4 gv = *(const float4*)(g + c0);
  float4 bv = *(const float4*)(be + c0);
  float4 o;
  o.x = (v[0]-mu)*rs*gv.x + bv.x;
  o.y = (v[1]-mu)*rs*gv.y + bv.y;
  o.z = (v[2]-mu)*rs*gv.z + bv.z;
  o.w = (v[3]-mu)*rs*gv.w + bv.w;
  *(float4*)(out + base + c0) = o;
}

// ---------------------------------------------------------------- launcher
extern "C" void kernel_launch(void* const* d_in, const int* in_sizes, int n_in,
                              void* d_out, int out_size, void* d_ws, size_t ws_size,
                              hipStream_t stream) {
  const float* x   = (const float*)d_in[0];
  const float* Wq  = (const float*)d_in[1];
  const float* bq  = (const float*)d_in[2];
  const float* Wk  = (const float*)d_in[3];
  const float* bk  = (const float*)d_in[4];
  const float* Wv  = (const float*)d_in[5];
  const float* bv  = (const float*)d_in[6];
  const float* W1  = (const float*)d_in[7];
  const float* b1  = (const float*)d_in[8];
  const float* W2  = (const float*)d_in[9];
  const float* b2  = (const float*)d_in[10];
  const float* g1  = (const float*)d_in[11];
  const float* be1 = (const float*)d_in[12];
  const float* g2  = (const float*)d_in[13];
  const float* be2 = (const float*)d_in[14];

  char* ws = (char*)d_ws;
  bf16* xb    = (bf16*)(ws + 0ull);
  bf16* WqkvT = (bf16*)(ws + 8388608ull);
  bf16* W1T   = (bf16*)(ws + 14680064ull);
  bf16* W2T   = (bf16*)(ws + 23068672ull);
  bf16* Qb    = (bf16*)(ws + 31457280ull);
  bf16* Kb    = (bf16*)(ws + 39845888ull);
  bf16* Vb    = (bf16*)(ws + 48234496ull);
  bf16* Vt    = (bf16*)(ws + 56623104ull);
  bf16* h1    = (bf16*)(ws + 31457280ull);   // aliases Q..Vt (dead after attention)
  bf16* attn  = (bf16*)(ws + 65011712ull);
  bf16* ln1   = (bf16*)(ws + 73400320ull);
  float* y2   = (float*)(ws + 65011712ull);  // aliases attn+ln1 (dead after FFN1)
  float* out  = (float*)d_out;

  convert_x<<<4096, 256, 0, stream>>>(x, xb);
  transpose_w<<<dim3(16, 16), 256, 0, stream>>>(Wq, WqkvT, 1024, 1024);
  transpose_w<<<dim3(16, 16), 256, 0, stream>>>(Wk, WqkvT + 1024 * 1024, 1024, 1024);
  transpose_w<<<dim3(16, 16), 256, 0, stream>>>(Wv, WqkvT + 2 * 1024 * 1024, 1024, 1024);
  transpose_w<<<dim3(64, 16), 256, 0, stream>>>(W1, W1T, 1024, 4096);
  transpose_w<<<dim3(16, 64), 256, 0, stream>>>(W2, W2T, 4096, 1024);

  gemm_bt<0><<<dim3(24, 32), 256, 0, stream>>>(xb, WqkvT, bq, bk, bv,
                                               (void*)Qb, (void*)Kb, (void*)Vb,
                                               4096, 3072, 1024);
  transpose_v<<<dim3(32, 32), 256, 0, stream>>>(Vb, Vt);
  flash_attn<<<dim3(16, 32), 256, 0, stream>>>(Qb, Kb, Vt, attn);
  ln_res<<<4096, 256, 0, stream>>>(attn, x, g1, be1, ln1);
  gemm_bt<1><<<dim3(32, 32), 256, 0, stream>>>(ln1, W1T, b1, nullptr, nullptr,
                                               (void*)h1, nullptr, nullptr,
                                               4096, 4096, 1024);
  gemm_bt<2><<<dim3(8, 32), 256, 0, stream>>>(h1, W2T, b2, nullptr, nullptr,
                                              (void*)y2, nullptr, nullptr,
                                              4096, 1024, 4096);
  ln2_kernel<<<4096, 256, 0, stream>>>(y2, g2, be2, out);
}